// Round 1
// baseline (12272.710 us; speedup 1.0000x reference)
//
#include <hip/hip_runtime.h>
#include <math.h>

// DreamBeliefTracker — RSSM scan, fp32-faithful baseline (round 1).
// Design notes:
//  * z is exactly one-hot in forward (y_hard + p - sg(p)) -> gather instead of GEMM for t>=1.
//  * All GEMMs fp32 vector (no fp32 MFMA on CDNA4); precision needed to avoid Gumbel-argmax flips.
//  * Split-K everywhere (M=256 starves tile parallelism); partial-sum reductions fused into
//    consumers (GRU / sample) or tiny combine kernels.
//  * Round-2 plan: swap GEMM engine to fp16 hi/lo 3-pass MFMA (fp32-grade error, ~3x faster).

constexpr int kB   = 256;   // batch
constexpr int kT   = 64;    // time steps
constexpr int kN1  = 1024;  // BELIEF == LATENT == MLP == STOCH*DISC
constexpr int kG3N = 3072;  // 3*BELIEF
constexpr int kActD = 6;

// ---------------------------------------------------------------- GEMM ------
// Block tile 128x128, BK=16, 256 threads, 8x8 per-thread micro-tile.
// A is M x K row-major from up to two concatenated sources (cols [0,cols1) from A1,
// [cols1,K) from A2; row stride == respective column count). W is K x N row-major.
// Each job computes a K-chunk partial into P (M x N).
struct GemmJob {
  const float* A1; const float* A2; const float* W; float* P;
  int cols1; int K; int N; int k0; int klen;
};
struct GemmJobs { GemmJob j[12]; };

__global__ __launch_bounds__(256) void k_gemm(GemmJobs js) {
  const GemmJob jb = js.j[blockIdx.z];
  const int N  = jb.N;
  const int m0 = blockIdx.x * 128;
  const int n0 = blockIdx.y * 128;
  __shared__ float As[16][132];   // [k][m], +4 pad
  __shared__ float Bs[16][132];   // [k][n], +4 pad
  float acc[8][8] = {{0.f}};
  const int tid  = threadIdx.x;
  const int tm   = (tid & 15) * 8;
  const int tn   = (tid >> 4) * 8;
  const int arow = tid >> 1;          // 0..127
  const int ak8  = (tid & 1) * 8;     // 0 or 8
  const int wk   = tid >> 4;          // 0..15
  const int wn   = (tid & 15) * 8;    // 0..120

  for (int kt = 0; kt < jb.klen; kt += 16) {
    const int kg = jb.k0 + kt;
    // ---- global loads (issued before the sync so they overlap prior compute)
    const float* Ap;
    if (kg < jb.cols1) Ap = jb.A1 + (size_t)(m0 + arow) * jb.cols1 + (kg + ak8);
    else               Ap = jb.A2 + (size_t)(m0 + arow) * (jb.K - jb.cols1) + (kg - jb.cols1 + ak8);
    const float4 av0 = *(const float4*)Ap;
    const float4 av1 = *(const float4*)(Ap + 4);
    const float* Wp = jb.W + (size_t)(kg + wk) * N + (n0 + wn);
    const float4 wv0 = *(const float4*)Wp;
    const float4 wv1 = *(const float4*)(Wp + 4);
    __syncthreads();                 // previous tile fully consumed
    As[ak8 + 0][arow] = av0.x; As[ak8 + 1][arow] = av0.y;
    As[ak8 + 2][arow] = av0.z; As[ak8 + 3][arow] = av0.w;
    As[ak8 + 4][arow] = av1.x; As[ak8 + 5][arow] = av1.y;
    As[ak8 + 6][arow] = av1.z; As[ak8 + 7][arow] = av1.w;
    *(float4*)&Bs[wk][wn]     = wv0;
    *(float4*)&Bs[wk][wn + 4] = wv1;
    __syncthreads();
#pragma unroll
    for (int kk = 0; kk < 16; ++kk) {
      float a[8], w[8];
      *(float4*)&a[0] = *(const float4*)&As[kk][tm];
      *(float4*)&a[4] = *(const float4*)&As[kk][tm + 4];
      *(float4*)&w[0] = *(const float4*)&Bs[kk][tn];
      *(float4*)&w[4] = *(const float4*)&Bs[kk][tn + 4];
#pragma unroll
      for (int i = 0; i < 8; ++i)
#pragma unroll
        for (int jj = 0; jj < 8; ++jj)
          acc[i][jj] = fmaf(a[i], w[jj], acc[i][jj]);
    }
  }
#pragma unroll
  for (int i = 0; i < 8; ++i) {
    float* row = jb.P + (size_t)(m0 + tm + i) * N + (n0 + tn);
    *(float4*)row       = make_float4(acc[i][0], acc[i][1], acc[i][2], acc[i][3]);
    *(float4*)(row + 4) = make_float4(acc[i][4], acc[i][5], acc[i][6], acc[i][7]);
  }
}

// ---------------------------------------------------- combine (split-K sum) --
struct CombJob { const float* P; const float* bias; float* out; int nparts; int silu; };
struct CombJobs { CombJob j[2]; };

__global__ __launch_bounds__(256) void k_combine(CombJobs js) {
  const CombJob jb = js.j[blockIdx.y];
  const int i = blockIdx.x * 256 + threadIdx.x;   // over kB*kN1
  float s = 0.f;
  for (int p = 0; p < jb.nparts; ++p) s += jb.P[(size_t)p * (kB * kN1) + i];
  s += jb.bias[i & (kN1 - 1)];
  if (jb.silu) s = s * (1.f / (1.f + expf(-s)));
  jb.out[i] = s;
}

// --------------------------------------------------------- LayerNorm + GRU --
__global__ __launch_bounds__(256) void k_gru(const float* Pg, const float* lns,
                                             const float* lnb, float* bbuf) {
  const int b = blockIdx.x;
  const int tid = threadIdx.x;
  __shared__ float sh[kG3N];
  __shared__ float red[8];
  float v[12];
  float sum = 0.f, sq = 0.f;
#pragma unroll
  for (int i = 0; i < 12; ++i) {
    const int j = tid + i * 256;
    float s = 0.f;
    for (int p = 0; p < 4; ++p) s += Pg[(size_t)p * (kB * kG3N) + (size_t)b * kG3N + j];
    v[i] = s; sum += s; sq += s * s;
  }
  for (int m = 1; m <= 32; m <<= 1) { sum += __shfl_xor(sum, m); sq += __shfl_xor(sq, m); }
  if ((tid & 63) == 0) { red[(tid >> 6) * 2] = sum; red[(tid >> 6) * 2 + 1] = sq; }
  __syncthreads();
  float ts = 0.f, tq = 0.f;
  for (int w = 0; w < 4; ++w) { ts += red[w * 2]; tq += red[w * 2 + 1]; }
  const float mu   = ts * (1.f / kG3N);
  const float var  = tq * (1.f / kG3N) - mu * mu;
  const float rinv = 1.f / sqrtf(var + 1e-3f);
#pragma unroll
  for (int i = 0; i < 12; ++i) {
    const int j = tid + i * 256;
    sh[j] = (v[i] - mu) * rinv * lns[j] + lnb[j];
  }
  __syncthreads();
#pragma unroll
  for (int i = 0; i < 4; ++i) {
    const int j = tid + i * 256;
    const float r = sh[j], c = sh[kN1 + j], u = sh[2 * kN1 + j];
    const float reset = 1.f / (1.f + expf(-r));
    const float cand  = tanhf(reset * c);
    const float upd   = 1.f / (1.f + expf(-(u - 1.f)));   // UPDATE_BIAS = -1
    const size_t o = (size_t)b * kN1 + j;
    bbuf[o] = upd * cand + (1.f - upd) * bbuf[o];
  }
}

// ------------------------------- softmax/unimix/KL + Gumbel-argmax sampling --
__global__ __launch_bounds__(1024) void k_sample(const float* Ppl, const float* Pol,
    const float* bp2, const float* bo2, const float* unz_t,
    int* z_idx, float* loss_t) {
  const int b = blockIdx.x;
  const int tid = threadIdx.x;            // g = tid>>5 (group), c = tid&31 (category)
  const size_t o = (size_t)b * kN1 + tid;
  float lp = 0.f, lo = 0.f;
  for (int p = 0; p < 4; ++p) {
    lp += Ppl[(size_t)p * (kB * kN1) + o];
    lo += Pol[(size_t)p * (kB * kN1) + o];
  }
  lp += bp2[tid]; lo += bo2[tid];
  lp = fminf(fmaxf(lp, -20.f), 20.f);     // CLIP
  lo = fminf(fmaxf(lo, -20.f), 20.f);
  // group softmax over 32 lanes (each group occupies one 32-lane half-wave)
  float mp = lp, mo = lo;
  for (int m = 1; m <= 16; m <<= 1) { mp = fmaxf(mp, __shfl_xor(mp, m)); mo = fmaxf(mo, __shfl_xor(mo, m)); }
  const float ep = expf(lp - mp), eo = expf(lo - mo);
  float sp = ep, so = eo;
  for (int m = 1; m <= 16; m <<= 1) { sp += __shfl_xor(sp, m); so += __shfl_xor(so, m); }
  const float pp = (ep / sp) * 0.99f + (0.01f / 32.f);   // unimix
  const float po = (eo / so) * 0.99f + (0.01f / 32.f);
  float kt = po * (logf(po + 1e-8f) - logf(pp + 1e-8f));
  for (int m = 1; m <= 16; m <<= 1) kt += __shfl_xor(kt, m);
  // gumbel-max (forward value of straight-through sample is exactly the one-hot)
  const float u = unz_t[o];
  const float g = -logf(-logf(u + 1e-6f) + 1e-6f);
  float vv = logf(fmaxf(po, 1e-6f)) + g;
  int ii = tid & 31;
  for (int m = 1; m <= 16; m <<= 1) {
    const float vo = __shfl_xor(vv, m);
    const int   io = __shfl_xor(ii, m);
    if (vo > vv || (vo == vv && io < ii)) { vv = vo; ii = io; }   // first-max on ties
  }
  __shared__ float skl[32];
  if ((tid & 31) == 0) {
    skl[tid >> 5] = kt;
    z_idx[b * 32 + (tid >> 5)] = ii;
  }
  __syncthreads();
  if (tid == 0) {
    float kl = 0.f;
    for (int gg = 0; gg < 32; ++gg) kl += skl[gg];
    const float dl = fmaxf(kl, 0.1f);     // FREE; kl_dyn == kl_rep in forward
    loss_t[b] = 1.0f * dl + 0.1f * dl;    // DYN_SCALE*dyn + REP_SCALE*rep
  }
}

// --------------------- input MLP layer 1 via one-hot gather (t >= 1) --------
__global__ __launch_bounds__(256) void k_input(const float* Wi1, const float* bi1,
    const int* z_idx, const float* act_t, float* h1) {
  const int b = blockIdx.y;
  const int j = blockIdx.x * 256 + threadIdx.x;
  __shared__ int   sidx[32];
  __shared__ float sact[kActD];
  if (threadIdx.x < 32) sidx[threadIdx.x] = z_idx[b * 32 + threadIdx.x];
  if (threadIdx.x >= 64 && threadIdx.x < 64 + kActD)
    sact[threadIdx.x - 64] = act_t[b * kActD + (threadIdx.x - 64)];
  __syncthreads();
  float s = bi1[j];
#pragma unroll
  for (int g = 0; g < 32; ++g) s += Wi1[(size_t)(g * 32 + sidx[g]) * kN1 + j];
#pragma unroll
  for (int k = 0; k < kActD; ++k) s += sact[k] * Wi1[(size_t)(kN1 + k) * kN1 + j];
  h1[(size_t)b * kN1 + j] = s * (1.f / (1.f + expf(-s)));   // silu
}

// ---------------- t = 0 finisher: dense-z partials + action part + silu -----
__global__ __launch_bounds__(256) void k_finish0(const float* P, const float* Wi1,
    const float* bi1, const float* act0, float* h1) {
  const int b = blockIdx.y;
  const int j = blockIdx.x * 256 + threadIdx.x;
  __shared__ float sact[kActD];
  if (threadIdx.x < kActD) sact[threadIdx.x] = act0[b * kActD + threadIdx.x];
  __syncthreads();
  float s = bi1[j];
  for (int p = 0; p < 8; ++p) s += P[(size_t)p * (kB * kN1) + (size_t)b * kN1 + j];
#pragma unroll
  for (int k = 0; k < kActD; ++k) s += sact[k] * Wi1[(size_t)(kN1 + k) * kN1 + j];
  h1[(size_t)b * kN1 + j] = s * (1.f / (1.f + expf(-s)));
}

// ---------------------------------------------------------------------------
extern "C" void kernel_launch(void* const* d_in, const int* in_sizes, int n_in,
                              void* d_out, int out_size, void* d_ws, size_t ws_size,
                              hipStream_t stream) {
  const float* b0   = (const float*)d_in[0];
  const float* z0   = (const float*)d_in[1];
  const float* acts = (const float*)d_in[2];
  const float* obs  = (const float*)d_in[3];
  const float* unz  = (const float*)d_in[4];
  const float* Wi1  = (const float*)d_in[5];
  const float* bi1  = (const float*)d_in[6];
  const float* Wi2  = (const float*)d_in[7];
  const float* bi2  = (const float*)d_in[8];
  const float* Wg   = (const float*)d_in[9];
  const float* lns  = (const float*)d_in[10];
  const float* lnb  = (const float*)d_in[11];
  const float* Wo1  = (const float*)d_in[12];
  const float* bo1  = (const float*)d_in[13];
  const float* Wo2  = (const float*)d_in[14];
  const float* bo2  = (const float*)d_in[15];
  const float* Wp1  = (const float*)d_in[16];
  const float* bp1  = (const float*)d_in[17];
  const float* Wp2  = (const float*)d_in[18];
  const float* bp2  = (const float*)d_in[19];
  float* out = (float*)d_out;

  // workspace carve (~26.3 MB)
  float* ws = (float*)d_ws;
  size_t off = 0;
  auto alloc = [&](size_t n) { float* p = ws + off; off += n; return p; };
  float* h1   = alloc((size_t)kB * kN1);
  float* inp  = alloc((size_t)kB * kN1);
  float* bbuf = alloc((size_t)kB * kN1);
  float* hp   = alloc((size_t)kB * kN1);
  float* ho   = alloc((size_t)kB * kN1);
  float* Pin  = alloc((size_t)8 * kB * kN1);   // dense-z / G2 / logit partials (reused)
  float* Pg   = alloc((size_t)4 * kB * kG3N);  // gates / hp / ho partials (reused)
  int*   z_idx = (int*)alloc((size_t)kB * 32);
  float* Php = Pg;
  float* Pho = Pg + (size_t)4 * kB * kN1;
  float* Ppl = Pin;
  float* Pol = Pin + (size_t)4 * kB * kN1;

  hipMemcpyAsync(bbuf, b0, sizeof(float) * (size_t)kB * kN1,
                 hipMemcpyDeviceToDevice, stream);

  for (int t = 0; t < kT; ++t) {
    const float* act_t = acts + (size_t)t * kB * kActD;
    const float* obs_t = obs  + (size_t)t * kB * kN1;
    const float* unz_t = unz  + (size_t)t * kB * kN1;

    if (t == 0) {   // dense z0 @ Wi1[z-rows]
      GemmJobs J{};
      for (int s = 0; s < 8; ++s)
        J.j[s] = { z0, nullptr, Wi1, Pin + (size_t)s * kB * kN1, 1024, 1024, kN1, s * 128, 128 };
      k_gemm<<<dim3(2, 8, 8), 256, 0, stream>>>(J);
      k_finish0<<<dim3(4, kB), 256, 0, stream>>>(Pin, Wi1, bi1, act_t, h1);
    } else {        // one-hot gather path
      k_input<<<dim3(4, kB), 256, 0, stream>>>(Wi1, bi1, z_idx, act_t, h1);
    }

    {  // G2: inp = h1 @ Wi2 + bi2
      GemmJobs J{};
      for (int s = 0; s < 8; ++s)
        J.j[s] = { h1, nullptr, Wi2, Pin + (size_t)s * kB * kN1, 1024, 1024, kN1, s * 128, 128 };
      k_gemm<<<dim3(2, 8, 8), 256, 0, stream>>>(J);
      CombJobs C{};
      C.j[0] = { Pin, bi2, inp, 8, 0 };
      k_combine<<<dim3(1024, 1), 256, 0, stream>>>(C);
    }

    {  // G3: gates = [inp, b] @ Wg  -> LN -> GRU (updates bbuf in place)
      GemmJobs J{};
      for (int s = 0; s < 4; ++s)
        J.j[s] = { inp, bbuf, Wg, Pg + (size_t)s * kB * kG3N, 1024, 2048, kG3N, s * 512, 512 };
      k_gemm<<<dim3(2, 24, 4), 256, 0, stream>>>(J);
      k_gru<<<dim3(kB), 256, 0, stream>>>(Pg, lns, lnb, bbuf);
    }

    {  // G45: hp = silu(b@Wp1+bp1) ; ho = silu([obs,b]@Wo1+bo1)
      GemmJobs J{};
      for (int s = 0; s < 4; ++s)
        J.j[s]     = { bbuf, nullptr, Wp1, Php + (size_t)s * kB * kN1, 1024, 1024, kN1, s * 256, 256 };
      for (int s = 0; s < 8; ++s)
        J.j[4 + s] = { obs_t, bbuf,   Wo1, Pho + (size_t)s * kB * kN1, 1024, 2048, kN1, s * 256, 256 };
      k_gemm<<<dim3(2, 8, 12), 256, 0, stream>>>(J);
      CombJobs C{};
      C.j[0] = { Php, bp1, hp, 4, 1 };
      C.j[1] = { Pho, bo1, ho, 8, 1 };
      k_combine<<<dim3(1024, 2), 256, 0, stream>>>(C);
    }

    {  // G67: prior/post logits, then sample + KL
      GemmJobs J{};
      for (int s = 0; s < 4; ++s)
        J.j[s]     = { hp, nullptr, Wp2, Ppl + (size_t)s * kB * kN1, 1024, 1024, kN1, s * 256, 256 };
      for (int s = 0; s < 4; ++s)
        J.j[4 + s] = { ho, nullptr, Wo2, Pol + (size_t)s * kB * kN1, 1024, 1024, kN1, s * 256, 256 };
      k_gemm<<<dim3(2, 8, 8), 256, 0, stream>>>(J);
      k_sample<<<dim3(kB), 1024, 0, stream>>>(Ppl, Pol, bp2, bo2, unz_t, z_idx,
                                              out + (size_t)t * kB);
    }
  }
}

// Round 2
// 7718.555 us; speedup vs baseline: 1.5900x; 1.5900x over previous
//
#include <hip/hip_runtime.h>
#include <math.h>

// DreamBeliefTracker — round 2: fp16 hi/lo split 3-pass MFMA GEMM engine.
//  * x = hi + lo*2^-12 (lo pre-scaled by 4096 -> fp16-normal, denorm-safe).
//  * acc1 = Ah*Wh ; acc2 = Ah*Wl + Al*Wh ; out = acc1 + acc2/4096  (error ~2^-22: fp32-grade,
//    round-1 proved fp32 gives ZERO argmax flips -> same trajectory).
//  * M-tile=256 (full batch): every weight byte read ONCE per step (L3-resident, ~54 MB/step).
//  * W converted fp32->hi/lo on the fly during staging (no weight-plane workspace).
//  * split-K for parallelism; partial sums combined in fused consumers.

typedef _Float16 f16;
typedef _Float16 f16x8 __attribute__((ext_vector_type(8)));
typedef float f32x4 __attribute__((ext_vector_type(4)));

constexpr int kB = 256, kN1 = 1024, kG3N = 3072, kActD = 6;
constexpr int kT = 64;
constexpr float kLoScale = 4096.f;
constexpr float kLoInv = 1.f / 4096.f;

__device__ inline void wr_planes(f16* hi, f16* lo, size_t i, float x) {
  f16 h = (f16)x;
  hi[i] = h;
  lo[i] = (f16)((x - (float)h) * kLoScale);
}

// ------------------------------------------------------------- MFMA GEMM ----
// Block: 256 threads (4 waves). Tile: M=256 (full), N=64, BK=32.
// A from up to two concatenated f16-plane sources (cols [0,cols1) = A1, rest A2).
// W: K x N row-major fp32, converted to hi/lo during staging, stored transposed
// [n][k] in LDS so B-fragments are contiguous ds_read_b128.
struct MJob {
  const f16* A1h; const f16* A1l; const f16* A2h; const f16* A2l;
  const float* W; float* P;
  int cols1, K, N, kchunk, nchunks;
};
struct MJobs { MJob j[2]; };

__global__ __launch_bounds__(256, 1) void k_mgemm(MJobs js) {
  const MJob jb = js.j[blockIdx.z];
  if ((int)blockIdx.y >= jb.nchunks) return;
  const int N = jb.N;
  const int n0 = blockIdx.x * 64;
  const int kbeg = blockIdx.y * jb.kchunk;
  const int kend = kbeg + jb.kchunk;

  __shared__ f16 As[2][256][40];   // [plane][m][k], stride 40 halves (80 B, 16B-aligned)
  __shared__ f16 Ws[2][64][40];    // [plane][n][k] (transposed W tile)

  const int t = threadIdx.x;
  const int lane = t & 63;
  const int wv = t >> 6;           // wave 0..3
  const int fr = lane & 15;        // fragment row/col lane
  const int quad = lane >> 4;      // k-quad
  const int mb = wv * 64;          // wave's m-base
  const int wn = t & 63;           // W staging: n within tile
  const int oct = t >> 6;          // W staging: k-octet

  f32x4 acc1[4][4], acc2[4][4];
#pragma unroll
  for (int i = 0; i < 4; ++i)
#pragma unroll
    for (int j = 0; j < 4; ++j)
#pragma unroll
      for (int r = 0; r < 4; ++r) { acc1[i][j][r] = 0.f; acc2[i][j][r] = 0.f; }

  for (int kg = kbeg; kg < kend; kg += 32) {
    // ---- global loads first (overlap previous iter's compute)
    const f16 *sh, *sl;
    if (kg < jb.cols1) {
      sh = jb.A1h + (size_t)t * jb.cols1 + kg;
      sl = jb.A1l + (size_t)t * jb.cols1 + kg;
    } else {
      const int c2 = jb.K - jb.cols1;
      sh = jb.A2h + (size_t)t * c2 + (kg - jb.cols1);
      sl = jb.A2l + (size_t)t * c2 + (kg - jb.cols1);
    }
    f16x8 ah[4], al[4];
#pragma unroll
    for (int q = 0; q < 4; ++q) {
      ah[q] = *(const f16x8*)(sh + q * 8);
      al[q] = *(const f16x8*)(sl + q * 8);
    }
    float wvf[8];
#pragma unroll
    for (int i = 0; i < 8; ++i)
      wvf[i] = jb.W[(size_t)(kg + oct * 8 + i) * N + n0 + wn];
    f16x8 wh, wl;
#pragma unroll
    for (int i = 0; i < 8; ++i) {
      f16 h = (f16)wvf[i];
      wh[i] = h;
      wl[i] = (f16)((wvf[i] - (float)h) * kLoScale);
    }

    __syncthreads();               // previous tile fully consumed
#pragma unroll
    for (int q = 0; q < 4; ++q) {
      *(f16x8*)&As[0][t][q * 8] = ah[q];
      *(f16x8*)&As[1][t][q * 8] = al[q];
    }
    *(f16x8*)&Ws[0][wn][oct * 8] = wh;
    *(f16x8*)&Ws[1][wn][oct * 8] = wl;
    __syncthreads();

    f16x8 Ah[4], Al[4], Wh[4], Wl[4];
#pragma unroll
    for (int mf = 0; mf < 4; ++mf) {
      Ah[mf] = *(const f16x8*)&As[0][mb + mf * 16 + fr][quad * 8];
      Al[mf] = *(const f16x8*)&As[1][mb + mf * 16 + fr][quad * 8];
    }
#pragma unroll
    for (int nf = 0; nf < 4; ++nf) {
      Wh[nf] = *(const f16x8*)&Ws[0][nf * 16 + fr][quad * 8];
      Wl[nf] = *(const f16x8*)&Ws[1][nf * 16 + fr][quad * 8];
    }
#pragma unroll
    for (int mf = 0; mf < 4; ++mf)
#pragma unroll
      for (int nf = 0; nf < 4; ++nf) {
        acc1[mf][nf] = __builtin_amdgcn_mfma_f32_16x16x32_f16(Ah[mf], Wh[nf], acc1[mf][nf], 0, 0, 0);
        acc2[mf][nf] = __builtin_amdgcn_mfma_f32_16x16x32_f16(Ah[mf], Wl[nf], acc2[mf][nf], 0, 0, 0);
        acc2[mf][nf] = __builtin_amdgcn_mfma_f32_16x16x32_f16(Al[mf], Wh[nf], acc2[mf][nf], 0, 0, 0);
      }
  }

  float* P = jb.P + (size_t)blockIdx.y * ((size_t)kB * N);
#pragma unroll
  for (int mf = 0; mf < 4; ++mf)
#pragma unroll
    for (int nf = 0; nf < 4; ++nf)
#pragma unroll
      for (int r = 0; r < 4; ++r) {
        const int row = mb + mf * 16 + quad * 4 + r;
        const int col = n0 + nf * 16 + fr;
        P[(size_t)row * N + col] = acc1[mf][nf][r] + acc2[mf][nf][r] * kLoInv;
      }
}

// --------------------------------------- combine split-K -> bias/silu -> planes
struct CJob { const float* P; const float* bias; f16* ohi; f16* olo; int nparts; int silu; };
struct CJobs { CJob j[2]; };

__global__ __launch_bounds__(256) void k_combine(CJobs js) {
  const CJob jb = js.j[blockIdx.y];
  const int i = blockIdx.x * 256 + threadIdx.x;
  float s = 0.f;
  for (int p = 0; p < jb.nparts; ++p) s += jb.P[(size_t)p * (kB * kN1) + i];
  s += jb.bias[i & (kN1 - 1)];
  if (jb.silu) s = s * (1.f / (1.f + expf(-s)));
  wr_planes(jb.ohi, jb.olo, i, s);
}

// ---------------- LayerNorm + GRU (+ per-step obs fp32 -> hi/lo conversion) --
__global__ __launch_bounds__(256) void k_gru(const float* Pg, const float* lns,
                                             const float* lnb, float* bbuf,
                                             f16* bh, f16* bl,
                                             const float* obs_t, f16* oh, f16* ol) {
  const int b = blockIdx.x;
  const int tid = threadIdx.x;
  __shared__ float sh[kG3N];
  __shared__ float red[8];
  float v[12];
  float sum = 0.f, sq = 0.f;
#pragma unroll
  for (int i = 0; i < 12; ++i) {
    const int j = tid + i * 256;
    float s = 0.f;
    for (int p = 0; p < 4; ++p) s += Pg[(size_t)p * (kB * kG3N) + (size_t)b * kG3N + j];
    v[i] = s; sum += s; sq += s * s;
  }
  // obs conversion for this step's posterior GEMM (hidden under the reduction)
#pragma unroll
  for (int i = 0; i < 4; ++i) {
    const int j = tid + i * 256;
    wr_planes(oh, ol, (size_t)b * kN1 + j, obs_t[(size_t)b * kN1 + j]);
  }
  for (int m = 1; m <= 32; m <<= 1) { sum += __shfl_xor(sum, m); sq += __shfl_xor(sq, m); }
  if ((tid & 63) == 0) { red[(tid >> 6) * 2] = sum; red[(tid >> 6) * 2 + 1] = sq; }
  __syncthreads();
  float ts = 0.f, tq = 0.f;
  for (int w = 0; w < 4; ++w) { ts += red[w * 2]; tq += red[w * 2 + 1]; }
  const float mu   = ts * (1.f / kG3N);
  const float var  = tq * (1.f / kG3N) - mu * mu;
  const float rinv = 1.f / sqrtf(var + 1e-3f);
#pragma unroll
  for (int i = 0; i < 12; ++i) {
    const int j = tid + i * 256;
    sh[j] = (v[i] - mu) * rinv * lns[j] + lnb[j];
  }
  __syncthreads();
#pragma unroll
  for (int i = 0; i < 4; ++i) {
    const int j = tid + i * 256;
    const float r = sh[j], c = sh[kN1 + j], u = sh[2 * kN1 + j];
    const float reset = 1.f / (1.f + expf(-r));
    const float cand  = tanhf(reset * c);
    const float upd   = 1.f / (1.f + expf(-(u - 1.f)));   // UPDATE_BIAS = -1
    const size_t o = (size_t)b * kN1 + j;
    const float bn = upd * cand + (1.f - upd) * bbuf[o];
    bbuf[o] = bn;
    wr_planes(bh, bl, o, bn);
  }
}

// ------------------------------- softmax/unimix/KL + Gumbel-argmax sampling --
__global__ __launch_bounds__(1024) void k_sample(const float* Ppl, const float* Pol,
    const float* bp2, const float* bo2, const float* unz_t,
    int* z_idx, float* loss_t) {
  const int b = blockIdx.x;
  const int tid = threadIdx.x;
  const size_t o = (size_t)b * kN1 + tid;
  float lp = 0.f, lo = 0.f;
  for (int p = 0; p < 4; ++p) {
    lp += Ppl[(size_t)p * (kB * kN1) + o];
    lo += Pol[(size_t)p * (kB * kN1) + o];
  }
  lp += bp2[tid]; lo += bo2[tid];
  lp = fminf(fmaxf(lp, -20.f), 20.f);
  lo = fminf(fmaxf(lo, -20.f), 20.f);
  float mp = lp, mo = lo;
  for (int m = 1; m <= 16; m <<= 1) { mp = fmaxf(mp, __shfl_xor(mp, m)); mo = fmaxf(mo, __shfl_xor(mo, m)); }
  const float ep = expf(lp - mp), eo = expf(lo - mo);
  float sp = ep, so = eo;
  for (int m = 1; m <= 16; m <<= 1) { sp += __shfl_xor(sp, m); so += __shfl_xor(so, m); }
  const float pp = (ep / sp) * 0.99f + (0.01f / 32.f);
  const float po = (eo / so) * 0.99f + (0.01f / 32.f);
  float kt = po * (logf(po + 1e-8f) - logf(pp + 1e-8f));
  for (int m = 1; m <= 16; m <<= 1) kt += __shfl_xor(kt, m);
  const float u = unz_t[o];
  const float g = -logf(-logf(u + 1e-6f) + 1e-6f);
  float vv = logf(fmaxf(po, 1e-6f)) + g;
  int ii = tid & 31;
  for (int m = 1; m <= 16; m <<= 1) {
    const float vo = __shfl_xor(vv, m);
    const int   io = __shfl_xor(ii, m);
    if (vo > vv || (vo == vv && io < ii)) { vv = vo; ii = io; }
  }
  __shared__ float skl[32];
  if ((tid & 31) == 0) {
    skl[tid >> 5] = kt;
    z_idx[b * 32 + (tid >> 5)] = ii;
  }
  __syncthreads();
  if (tid == 0) {
    float kl = 0.f;
    for (int gg = 0; gg < 32; ++gg) kl += skl[gg];
    const float dl = fmaxf(kl, 0.1f);
    loss_t[b] = 1.0f * dl + 0.1f * dl;
  }
}

// --------------------- input MLP layer 1 via one-hot gather (t >= 1) --------
__global__ __launch_bounds__(256) void k_input(const float* Wi1, const float* bi1,
    const int* z_idx, const float* act_t, f16* h1h, f16* h1l) {
  const int b = blockIdx.y;
  const int j = blockIdx.x * 256 + threadIdx.x;
  __shared__ int   sidx[32];
  __shared__ float sact[kActD];
  if (threadIdx.x < 32) sidx[threadIdx.x] = z_idx[b * 32 + threadIdx.x];
  if (threadIdx.x >= 64 && threadIdx.x < 64 + kActD)
    sact[threadIdx.x - 64] = act_t[b * kActD + (threadIdx.x - 64)];
  __syncthreads();
  float s = bi1[j];
#pragma unroll
  for (int g = 0; g < 32; ++g) s += Wi1[(size_t)(g * 32 + sidx[g]) * kN1 + j];
#pragma unroll
  for (int k = 0; k < kActD; ++k) s += sact[k] * Wi1[(size_t)(kN1 + k) * kN1 + j];
  s = s * (1.f / (1.f + expf(-s)));
  wr_planes(h1h, h1l, (size_t)b * kN1 + j, s);
}

// ---------------- t = 0 finisher: dense-z partials + action part + silu -----
__global__ __launch_bounds__(256) void k_finish0(const float* P, const float* Wi1,
    const float* bi1, const float* act0, f16* h1h, f16* h1l) {
  const int b = blockIdx.y;
  const int j = blockIdx.x * 256 + threadIdx.x;
  __shared__ float sact[kActD];
  if (threadIdx.x < kActD) sact[threadIdx.x] = act0[b * kActD + threadIdx.x];
  __syncthreads();
  float s = bi1[j];
  for (int p = 0; p < 8; ++p) s += P[(size_t)p * (kB * kN1) + (size_t)b * kN1 + j];
#pragma unroll
  for (int k = 0; k < kActD; ++k) s += sact[k] * Wi1[(size_t)(kN1 + k) * kN1 + j];
  s = s * (1.f / (1.f + expf(-s)));
  wr_planes(h1h, h1l, (size_t)b * kN1 + j, s);
}

// ---------------------- setup: z0 + b0 -> planes / fp32 state ---------------
__global__ __launch_bounds__(256) void k_setup(const float* z0, const float* b0,
    f16* z0h, f16* z0l, float* bbuf, f16* bh, f16* bl) {
  const int i = blockIdx.x * 256 + threadIdx.x;
  wr_planes(z0h, z0l, i, z0[i]);
  const float b = b0[i];
  bbuf[i] = b;
  wr_planes(bh, bl, i, b);
}

// ---------------------------------------------------------------------------
extern "C" void kernel_launch(void* const* d_in, const int* in_sizes, int n_in,
                              void* d_out, int out_size, void* d_ws, size_t ws_size,
                              hipStream_t stream) {
  const float* b0   = (const float*)d_in[0];
  const float* z0   = (const float*)d_in[1];
  const float* acts = (const float*)d_in[2];
  const float* obs  = (const float*)d_in[3];
  const float* unz  = (const float*)d_in[4];
  const float* Wi1  = (const float*)d_in[5];
  const float* bi1  = (const float*)d_in[6];
  const float* Wi2  = (const float*)d_in[7];
  const float* bi2  = (const float*)d_in[8];
  const float* Wg   = (const float*)d_in[9];
  const float* lns  = (const float*)d_in[10];
  const float* lnb  = (const float*)d_in[11];
  const float* Wo1  = (const float*)d_in[12];
  const float* bo1  = (const float*)d_in[13];
  const float* Wo2  = (const float*)d_in[14];
  const float* bo2  = (const float*)d_in[15];
  const float* Wp1  = (const float*)d_in[16];
  const float* bp1  = (const float*)d_in[17];
  const float* Wp2  = (const float*)d_in[18];
  const float* bp2  = (const float*)d_in[19];
  float* out = (float*)d_out;

  // ---- workspace carve (~29 MB)
  char* wsb = (char*)d_ws;
  size_t off = 0;
  auto allocB = [&](size_t bytes) { char* p = wsb + off; off += (bytes + 255) & ~(size_t)255; return p; };
  const size_t PL = (size_t)kB * kN1;          // 262144 elements
  f16* h1h  = (f16*)allocB(PL * 2);  f16* h1l  = (f16*)allocB(PL * 2);
  f16* inph = (f16*)allocB(PL * 2);  f16* inpl = (f16*)allocB(PL * 2);
  f16* bh   = (f16*)allocB(PL * 2);  f16* bl   = (f16*)allocB(PL * 2);
  f16* hph  = (f16*)allocB(PL * 2);  f16* hpl  = (f16*)allocB(PL * 2);
  f16* hoh  = (f16*)allocB(PL * 2);  f16* hol  = (f16*)allocB(PL * 2);
  f16* z0h  = (f16*)allocB(PL * 2);  f16* z0l  = (f16*)allocB(PL * 2);
  f16* obsh = (f16*)allocB(PL * 2);  f16* obsl = (f16*)allocB(PL * 2);
  float* bbuf = (float*)allocB(PL * 4);
  float* Pin  = (float*)allocB((size_t)8 * PL * 4);            // 8 x (256x1024) partials
  float* Pg   = (float*)allocB((size_t)4 * kB * kG3N * 4);     // 4 x (256x3072) partials
  int*   z_idx = (int*)allocB((size_t)kB * 32 * 4);
  float* Php = Pg;                                // 4 parts
  float* Pho = Pg + (size_t)4 * PL;               // 8 parts (fits: 4*3072 = 12*1024)
  float* Ppl = Pin;                               // 4 parts
  float* Pol = Pin + (size_t)4 * PL;              // 4 parts

  k_setup<<<dim3(1024), 256, 0, stream>>>(z0, b0, z0h, z0l, bbuf, bh, bl);

  for (int t = 0; t < kT; ++t) {
    const float* act_t = acts + (size_t)t * kB * kActD;
    const float* obs_t = obs  + (size_t)t * kB * kN1;
    const float* unz_t = unz  + (size_t)t * kB * kN1;

    if (t == 0) {   // dense z0 @ Wi1[0:1024,:]
      MJobs J{};
      J.j[0] = { z0h, z0l, nullptr, nullptr, Wi1, Pin, 1024, 1024, 1024, 128, 8 };
      k_mgemm<<<dim3(16, 8, 1), 256, 0, stream>>>(J);
      k_finish0<<<dim3(4, kB), 256, 0, stream>>>(Pin, Wi1, bi1, act_t, h1h, h1l);
    } else {        // one-hot gather path
      k_input<<<dim3(4, kB), 256, 0, stream>>>(Wi1, bi1, z_idx, act_t, h1h, h1l);
    }

    {  // G2: inp = h1 @ Wi2 + bi2
      MJobs J{};
      J.j[0] = { h1h, h1l, nullptr, nullptr, Wi2, Pin, 1024, 1024, 1024, 128, 8 };
      k_mgemm<<<dim3(16, 8, 1), 256, 0, stream>>>(J);
      CJobs C{};
      C.j[0] = { Pin, bi2, inph, inpl, 8, 0 };
      k_combine<<<dim3(1024, 1), 256, 0, stream>>>(C);
    }

    {  // G3: gates = [inp, b] @ Wg -> LN -> GRU (+ obs conversion for G45)
      MJobs J{};
      J.j[0] = { inph, inpl, bh, bl, Wg, Pg, 1024, 2048, kG3N, 512, 4 };
      k_mgemm<<<dim3(48, 4, 1), 256, 0, stream>>>(J);
      k_gru<<<dim3(kB), 256, 0, stream>>>(Pg, lns, lnb, bbuf, bh, bl, obs_t, obsh, obsl);
    }

    {  // G45: hp = silu(b@Wp1+bp1) ; ho = silu([obs,b]@Wo1+bo1)
      MJobs J{};
      J.j[0] = { bh, bl, nullptr, nullptr, Wp1, Php, 1024, 1024, 1024, 256, 4 };
      J.j[1] = { obsh, obsl, bh, bl,       Wo1, Pho, 1024, 2048, 1024, 256, 8 };
      k_mgemm<<<dim3(16, 8, 2), 256, 0, stream>>>(J);
      CJobs C{};
      C.j[0] = { Php, bp1, hph, hpl, 4, 1 };
      C.j[1] = { Pho, bo1, hoh, hol, 8, 1 };
      k_combine<<<dim3(1024, 2), 256, 0, stream>>>(C);
    }

    {  // G67: prior/post logits, then sample + KL
      MJobs J{};
      J.j[0] = { hph, hpl, nullptr, nullptr, Wp2, Ppl, 1024, 1024, 1024, 256, 4 };
      J.j[1] = { hoh, hol, nullptr, nullptr, Wo2, Pol, 1024, 1024, 1024, 256, 4 };
      k_mgemm<<<dim3(16, 4, 2), 256, 0, stream>>>(J);
      k_sample<<<dim3(kB), 1024, 0, stream>>>(Ppl, Pol, bp2, bo2, unz_t, z_idx,
                                              out + (size_t)t * kB);
    }
  }
}